// Round 3
// baseline (58727.478 us; speedup 1.0000x reference)
//
#include <hip/hip_runtime.h>
#include <hip/hip_cooperative_groups.h>

namespace cg = cooperative_groups;

#define B_ 64
#define T_ 512
#define D_ 1024
#define H_ 1024
#define NG_ 4096   // 4*H

// ---------------- h transpose helpers ----------------
__global__ __launch_bounds__(256) void k_trans_h_fwd(const float* __restrict__ h,
                                                     float* __restrict__ hT) {
  int idx = blockIdx.x * 256 + threadIdx.x;  // idx = k*64 + b
  int b = idx & 63;
  int k = idx >> 6;
  hT[idx] = h[b * H_ + k];
}

__global__ __launch_bounds__(256) void k_trans_h_back(const float* __restrict__ hT,
                                                      float* __restrict__ h) {
  int idx = blockIdx.x * 256 + threadIdx.x;  // idx = b*1024 + k
  int k = idx & (H_ - 1);
  int b = idx >> 10;
  h[idx] = hT[k * 64 + b];
}

// ---------------- Gx = x@Wi + bias, batched over a time chunk ----------------
// Grid: (256 col-blocks, Tc). Block: 512 threads (8 waves).
// Output layout: gx[trel][cb][b][c*4+g]
__global__ __launch_bounds__(512) void k_gx(
    const float* __restrict__ x,     // [64][512][1024]
    const float* __restrict__ Wi,    // [1024][4096]
    const float* __restrict__ bias,  // [4096]
    float* __restrict__ gx,          // [Tc][256][64][16]
    int t0) {
  __shared__ float xt[64 * 65];
  __shared__ float red[8 * 64 * 17];

  const int tid = threadIdx.x;
  const int lane = tid & 63;
  const int w = tid >> 6;
  const int hbase = blockIdx.x * 4;
  const int t = t0 + blockIdx.y;

  float acc[4][4];
#pragma unroll
  for (int c = 0; c < 4; ++c)
#pragma unroll
    for (int g = 0; g < 4; ++g) acc[c][g] = 0.f;

  for (int kt = 0; kt < 16; ++kt) {
    __syncthreads();
#pragma unroll
    for (int p = 0; p < 8; ++p) {
      int r = p * 8 + (tid >> 6);
      int dd = tid & 63;
      xt[dd * 65 + r] = x[(size_t)r * (T_ * D_) + (size_t)t * D_ + kt * 64 + dd];
    }
    __syncthreads();
    const int kkbase = w * 8;
#pragma unroll
    for (int kk = kkbase; kk < kkbase + 8; ++kk) {
      const int k = kt * 64 + kk;
      const float xv = xt[kk * 65 + lane];
#pragma unroll
      for (int g = 0; g < 4; ++g) {
        const float4 wi = *(const float4*)(Wi + (size_t)k * NG_ + g * H_ + hbase);
        acc[0][g] = fmaf(xv, wi.x, acc[0][g]);
        acc[1][g] = fmaf(xv, wi.y, acc[1][g]);
        acc[2][g] = fmaf(xv, wi.z, acc[2][g]);
        acc[3][g] = fmaf(xv, wi.w, acc[3][g]);
      }
    }
  }

#pragma unroll
  for (int c = 0; c < 4; ++c)
#pragma unroll
    for (int g = 0; g < 4; ++g) red[(w * 64 + lane) * 17 + c * 4 + g] = acc[c][g];
  __syncthreads();

  if (tid < 256) {
    const int b = tid >> 2;
    const int c = tid & 3;
    const int h = hbase + c;
    float4 v;
    float* vp = &v.x;
#pragma unroll
    for (int g = 0; g < 4; ++g) {
      float s = bias[g * H_ + h];
#pragma unroll
      for (int ww = 0; ww < 8; ++ww) s += red[(ww * 64 + b) * 17 + c * 4 + g];
      vp[g] = s;
    }
    *(float4*)(gx + ((size_t)(blockIdx.y * 256 + blockIdx.x) * 64 + b) * 16 + c * 4) = v;
  }
}

// ---------------- persistent cooperative recurrence ----------------
// Grid: 256 blocks x 512 threads, 1 block/CU. Dynamic LDS:
//   wlds [1024][16] f32 = 64 KB  (this block's Wh column-slice, staged once)
//   red  [8][64][17]    = 34 KB  (cross-wave k-split reduction)
__global__ __launch_bounds__(512) void k_recur(
    const float* __restrict__ Wh,     // [1024][4096]
    const float* __restrict__ gx,     // [tc][256][64][16] (bias folded)
    float* __restrict__ hA,           // hT ping [1024][64]
    float* __restrict__ hB,           // hT pong [1024][64]
    float* __restrict__ c_state,      // [64][1024] in-place
    float* __restrict__ ys,           // [64][512][1024]
    int t0, int tc) {
  extern __shared__ float smem[];
  float* wlds = smem;           // 16384 floats
  float* red = smem + 16384;    // 8704 floats

  cg::grid_group grid = cg::this_grid();

  const int tid = threadIdx.x;
  const int lane = tid & 63;
  const int w = tid >> 6;
  const int hbase = blockIdx.x * 4;

  // stage this block's Wh slice: wlds[k*16 + g*4 + c] = Wh[k][g*1024 + hbase + c]
  for (int idx = tid; idx < 4096; idx += 512) {
    const int k = idx >> 2;
    const int g = idx & 3;
    const float4 v = *(const float4*)(Wh + (size_t)k * NG_ + g * H_ + hbase);
    *(float4*)(wlds + k * 16 + g * 4) = v;
  }
  __syncthreads();

  for (int tt = 0; tt < tc; ++tt) {
    const int t = t0 + tt;
    const float* hin = (t & 1) ? hB : hA;
    float* hout = (t & 1) ? hA : hB;

    float acc[4][4];
#pragma unroll
    for (int c = 0; c < 4; ++c)
#pragma unroll
      for (int g = 0; g < 4; ++g) acc[c][g] = 0.f;

    const int k0 = w * 128;
#pragma unroll 8
    for (int k = k0; k < k0 + 128; ++k) {
      const float hv = hin[k * 64 + lane];
      const float4 w0 = *(const float4*)(wlds + k * 16);
      const float4 w1 = *(const float4*)(wlds + k * 16 + 4);
      const float4 w2 = *(const float4*)(wlds + k * 16 + 8);
      const float4 w3 = *(const float4*)(wlds + k * 16 + 12);
      acc[0][0] = fmaf(hv, w0.x, acc[0][0]);
      acc[1][0] = fmaf(hv, w0.y, acc[1][0]);
      acc[2][0] = fmaf(hv, w0.z, acc[2][0]);
      acc[3][0] = fmaf(hv, w0.w, acc[3][0]);
      acc[0][1] = fmaf(hv, w1.x, acc[0][1]);
      acc[1][1] = fmaf(hv, w1.y, acc[1][1]);
      acc[2][1] = fmaf(hv, w1.z, acc[2][1]);
      acc[3][1] = fmaf(hv, w1.w, acc[3][1]);
      acc[0][2] = fmaf(hv, w2.x, acc[0][2]);
      acc[1][2] = fmaf(hv, w2.y, acc[1][2]);
      acc[2][2] = fmaf(hv, w2.z, acc[2][2]);
      acc[3][2] = fmaf(hv, w2.w, acc[3][2]);
      acc[0][3] = fmaf(hv, w3.x, acc[0][3]);
      acc[1][3] = fmaf(hv, w3.y, acc[1][3]);
      acc[2][3] = fmaf(hv, w3.z, acc[2][3]);
      acc[3][3] = fmaf(hv, w3.w, acc[3][3]);
    }

#pragma unroll
    for (int c = 0; c < 4; ++c)
#pragma unroll
      for (int g = 0; g < 4; ++g) red[(w * 64 + lane) * 17 + c * 4 + g] = acc[c][g];
    __syncthreads();

    if (tid < 256) {
      const int b = tid >> 2;
      const int c = tid & 3;
      const int h = hbase + c;
      const float4 gxv =
          *(const float4*)(gx + ((size_t)(tt * 256 + blockIdx.x) * 64 + b) * 16 + c * 4);
      const float* gp = &gxv.x;
      float v[4];
#pragma unroll
      for (int g = 0; g < 4; ++g) {
        float s = gp[g];
#pragma unroll
        for (int ww = 0; ww < 8; ++ww) s += red[(ww * 64 + b) * 17 + c * 4 + g];
        v[g] = s;
      }
      const float cold = c_state[b * H_ + h];
      const float si = 1.f / (1.f + expf(-v[0]));
      const float sf = 1.f / (1.f + expf(-v[1]));
      const float gt = tanhf(v[2]);
      const float so = 1.f / (1.f + expf(-v[3]));
      const float cn = sf * cold + si * gt;
      const float hn = so * tanhf(cn);
      c_state[b * H_ + h] = cn;
      hout[h * 64 + b] = hn;
      ys[(size_t)b * (T_ * H_) + (size_t)t * H_ + h] = hn;
    }
    grid.sync();
  }
}

// ---------------- fallback: fused step (tiny ws) ----------------
__global__ __launch_bounds__(512) void k_lstm_step_fused(
    const float* __restrict__ xsrc, const float* __restrict__ Wi,
    const float* __restrict__ Wh, const float* __restrict__ bias,
    const float* __restrict__ hT_in, float* __restrict__ hT_out,
    float* __restrict__ c_state, float* __restrict__ ys_t) {
  __shared__ float red[8 * 64 * 17];
  const int tid = threadIdx.x;
  const int lane = tid & 63;
  const int w = tid >> 6;
  const int hbase = blockIdx.x * 4;
  float acc[4][4];
#pragma unroll
  for (int c = 0; c < 4; ++c)
#pragma unroll
    for (int g = 0; g < 4; ++g) acc[c][g] = 0.f;
  const int k0 = w * 128;
#pragma unroll 2
  for (int k = k0; k < k0 + 128; ++k) {
    const float hv = hT_in[k * 64 + lane];
    const float xv = xsrc[(size_t)lane * (T_ * D_) + k];
#pragma unroll
    for (int g = 0; g < 4; ++g) {
      const float4 wh = *(const float4*)(Wh + (size_t)k * NG_ + g * H_ + hbase);
      const float4 wi = *(const float4*)(Wi + (size_t)k * NG_ + g * H_ + hbase);
      acc[0][g] = fmaf(hv, wh.x, acc[0][g]);
      acc[1][g] = fmaf(hv, wh.y, acc[1][g]);
      acc[2][g] = fmaf(hv, wh.z, acc[2][g]);
      acc[3][g] = fmaf(hv, wh.w, acc[3][g]);
      acc[0][g] = fmaf(xv, wi.x, acc[0][g]);
      acc[1][g] = fmaf(xv, wi.y, acc[1][g]);
      acc[2][g] = fmaf(xv, wi.z, acc[2][g]);
      acc[3][g] = fmaf(xv, wi.w, acc[3][g]);
    }
  }
#pragma unroll
  for (int c = 0; c < 4; ++c)
#pragma unroll
    for (int g = 0; g < 4; ++g) red[(w * 64 + lane) * 17 + c * 4 + g] = acc[c][g];
  __syncthreads();
  if (tid < 256) {
    const int b = tid >> 2;
    const int c = tid & 3;
    const int h = hbase + c;
    float v[4];
#pragma unroll
    for (int g = 0; g < 4; ++g) {
      float s = bias[g * H_ + h];
#pragma unroll
      for (int ww = 0; ww < 8; ++ww) s += red[(ww * 64 + b) * 17 + c * 4 + g];
      v[g] = s;
    }
    const float cold = c_state[b * H_ + h];
    const float si = 1.f / (1.f + expf(-v[0]));
    const float sf = 1.f / (1.f + expf(-v[1]));
    const float gt = tanhf(v[2]);
    const float so = 1.f / (1.f + expf(-v[3]));
    const float cn = sf * cold + si * gt;
    const float hn = so * tanhf(cn);
    c_state[b * H_ + h] = cn;
    hT_out[h * 64 + b] = hn;
    ys_t[(size_t)b * (T_ * H_) + h] = hn;
  }
}

extern "C" void kernel_launch(void* const* d_in, const int* in_sizes, int n_in,
                              void* d_out, int out_size, void* d_ws, size_t ws_size,
                              hipStream_t stream) {
  const float* c0   = (const float*)d_in[0];
  const float* h0   = (const float*)d_in[1];
  const float* x    = (const float*)d_in[2];
  const float* Wi   = (const float*)d_in[3];
  const float* Wh   = (const float*)d_in[4];
  const float* bias = (const float*)d_in[5];

  float* out     = (float*)d_out;
  float* c_state = out;
  float* h_final = out + B_ * H_;
  float* ys      = out + 2 * B_ * H_;

  const size_t hbytes = (size_t)B_ * H_ * sizeof(float);
  float* hA = (float*)d_ws;
  float* hB = hA + B_ * H_;
  float* gxbuf = hB + B_ * H_;

  const size_t slice = (size_t)256 * 64 * 16 * sizeof(float);  // 1 MB per t
  size_t avail = (ws_size > 2 * hbytes) ? ws_size - 2 * hbytes : 0;
  int Tc = (int)(avail / slice);
  if (Tc > T_) Tc = T_;

  hipMemcpyAsync(c_state, c0, hbytes, hipMemcpyDeviceToDevice, stream);
  k_trans_h_fwd<<<B_ * H_ / 256, 256, 0, stream>>>(h0, hA);

  const unsigned smem_recur = (16384 + 8704) * sizeof(float);  // 100352 B

  if (Tc >= 1) {
    for (int t0 = 0; t0 < T_; t0 += Tc) {
      const int tc = (T_ - t0 < Tc) ? (T_ - t0) : Tc;
      dim3 gg(256, tc);
      k_gx<<<gg, 512, 0, stream>>>(x, Wi, bias, gxbuf, t0);
      int t0v = t0, tcv = tc;
      void* args[] = {(void*)&Wh,      (void*)&gxbuf, (void*)&hA,
                      (void*)&hB,      (void*)&c_state, (void*)&ys,
                      (void*)&t0v,     (void*)&tcv};
      hipLaunchCooperativeKernel((void*)k_recur, dim3(256), dim3(512), args,
                                 smem_recur, stream);
    }
  } else {
    for (int t = 0; t < T_; ++t) {
      const float* hin = (t & 1) ? hB : hA;
      float* hout      = (t & 1) ? hA : hB;
      k_lstm_step_fused<<<256, 512, 0, stream>>>(
          x + (size_t)t * D_, Wi, Wh, bias, hin, hout, c_state,
          ys + (size_t)t * H_);
    }
  }
  k_trans_h_back<<<B_ * H_ / 256, 256, 0, stream>>>(hA, h_final);
}

// Round 4
// 57486.322 us; speedup vs baseline: 1.0216x; 1.0216x over previous
//
#include <hip/hip_runtime.h>
#include <hip/hip_cooperative_groups.h>

#define B_ 64
#define T_ 512
#define D_ 1024
#define H_ 1024
#define NG_ 4096   // 4*H
#define NBLK 256   // blocks in the persistent recurrence kernel

// ---------------- h transpose helpers ----------------
__global__ __launch_bounds__(256) void k_trans_h_fwd(const float* __restrict__ h,
                                                     float* __restrict__ hT) {
  int idx = blockIdx.x * 256 + threadIdx.x;  // idx = k*64 + b
  int b = idx & 63;
  int k = idx >> 6;
  hT[idx] = h[b * H_ + k];
}

__global__ __launch_bounds__(256) void k_trans_h_back(const float* __restrict__ hT,
                                                      float* __restrict__ h) {
  int idx = blockIdx.x * 256 + threadIdx.x;  // idx = b*1024 + k
  int k = idx & (H_ - 1);
  int b = idx >> 10;
  h[idx] = hT[k * 64 + b];
}

// ---------------- Gx = x@Wi + bias, batched over a time chunk ----------------
__global__ __launch_bounds__(512) void k_gx(
    const float* __restrict__ x,     // [64][512][1024]
    const float* __restrict__ Wi,    // [1024][4096]
    const float* __restrict__ bias,  // [4096]
    float* __restrict__ gx,          // [Tc][256][64][16]
    int t0) {
  __shared__ float xt[64 * 65];
  __shared__ float red[8 * 64 * 17];

  const int tid = threadIdx.x;
  const int lane = tid & 63;
  const int w = tid >> 6;
  const int hbase = blockIdx.x * 4;
  const int t = t0 + blockIdx.y;

  float acc[4][4];
#pragma unroll
  for (int c = 0; c < 4; ++c)
#pragma unroll
    for (int g = 0; g < 4; ++g) acc[c][g] = 0.f;

  for (int kt = 0; kt < 16; ++kt) {
    __syncthreads();
#pragma unroll
    for (int p = 0; p < 8; ++p) {
      int r = p * 8 + (tid >> 6);
      int dd = tid & 63;
      xt[dd * 65 + r] = x[(size_t)r * (T_ * D_) + (size_t)t * D_ + kt * 64 + dd];
    }
    __syncthreads();
    const int kkbase = w * 8;
#pragma unroll
    for (int kk = kkbase; kk < kkbase + 8; ++kk) {
      const int k = kt * 64 + kk;
      const float xv = xt[kk * 65 + lane];
#pragma unroll
      for (int g = 0; g < 4; ++g) {
        const float4 wi = *(const float4*)(Wi + (size_t)k * NG_ + g * H_ + hbase);
        acc[0][g] = fmaf(xv, wi.x, acc[0][g]);
        acc[1][g] = fmaf(xv, wi.y, acc[1][g]);
        acc[2][g] = fmaf(xv, wi.z, acc[2][g]);
        acc[3][g] = fmaf(xv, wi.w, acc[3][g]);
      }
    }
  }

#pragma unroll
  for (int c = 0; c < 4; ++c)
#pragma unroll
    for (int g = 0; g < 4; ++g) red[(w * 64 + lane) * 17 + c * 4 + g] = acc[c][g];
  __syncthreads();

  if (tid < 256) {
    const int b = tid >> 2;
    const int c = tid & 3;
    const int h = hbase + c;
    float4 v;
    float* vp = &v.x;
#pragma unroll
    for (int g = 0; g < 4; ++g) {
      float s = bias[g * H_ + h];
#pragma unroll
      for (int ww = 0; ww < 8; ++ww) s += red[(ww * 64 + b) * 17 + c * 4 + g];
      vp[g] = s;
    }
    *(float4*)(gx + ((size_t)(blockIdx.y * 256 + blockIdx.x) * 64 + b) * 16 + c * 4) = v;
  }
}

// ---------------- persistent recurrence with lightweight grid barrier ----------------
// Grid: 256 blocks x 512 threads, 1 block/CU (98KB dynamic LDS).
__global__ __launch_bounds__(512) void k_recur(
    const float* __restrict__ Wh,     // [1024][4096]
    const float* __restrict__ gx,     // [tc][256][64][16] (bias folded)
    float* __restrict__ hA,           // hT ping [1024][64]
    float* __restrict__ hB,           // hT pong [1024][64]
    float* __restrict__ c_state,      // [64][1024] in-place
    float* __restrict__ ys,           // [64][512][1024]
    unsigned* __restrict__ bar,       // monotonic barrier counter (zeroed per launch)
    int t0, int tc) {
  extern __shared__ float smem[];
  float* wlds = smem;           // 16384 floats = 64 KB
  float* red = smem + 16384;    // 8704 floats = 34 KB

  const int tid = threadIdx.x;
  const int lane = tid & 63;
  const int w = tid >> 6;
  const int hbase = blockIdx.x * 4;

  // stage this block's Wh slice once: wlds[k*16 + g*4 + c]
  for (int idx = tid; idx < 4096; idx += 512) {
    const int k = idx >> 2;
    const int g = idx & 3;
    const float4 v = *(const float4*)(Wh + (size_t)k * NG_ + g * H_ + hbase);
    *(float4*)(wlds + k * 16 + g * 4) = v;
  }
  __syncthreads();

  for (int tt = 0; tt < tc; ++tt) {
    const int t = t0 + tt;
    const float* hin = (t & 1) ? hB : hA;
    float* hout = (t & 1) ? hA : hB;

    float acc[4][4];
#pragma unroll
    for (int c = 0; c < 4; ++c)
#pragma unroll
      for (int g = 0; g < 4; ++g) acc[c][g] = 0.f;

    const int k0 = w * 128;
#pragma unroll 8
    for (int k = k0; k < k0 + 128; ++k) {
      const float hv = hin[k * 64 + lane];
      const float4 w0 = *(const float4*)(wlds + k * 16);
      const float4 w1 = *(const float4*)(wlds + k * 16 + 4);
      const float4 w2 = *(const float4*)(wlds + k * 16 + 8);
      const float4 w3 = *(const float4*)(wlds + k * 16 + 12);
      acc[0][0] = fmaf(hv, w0.x, acc[0][0]);
      acc[1][0] = fmaf(hv, w0.y, acc[1][0]);
      acc[2][0] = fmaf(hv, w0.z, acc[2][0]);
      acc[3][0] = fmaf(hv, w0.w, acc[3][0]);
      acc[0][1] = fmaf(hv, w1.x, acc[0][1]);
      acc[1][1] = fmaf(hv, w1.y, acc[1][1]);
      acc[2][1] = fmaf(hv, w1.z, acc[2][1]);
      acc[3][1] = fmaf(hv, w1.w, acc[3][1]);
      acc[0][2] = fmaf(hv, w2.x, acc[0][2]);
      acc[1][2] = fmaf(hv, w2.y, acc[1][2]);
      acc[2][2] = fmaf(hv, w2.z, acc[2][2]);
      acc[3][2] = fmaf(hv, w2.w, acc[3][2]);
      acc[0][3] = fmaf(hv, w3.x, acc[0][3]);
      acc[1][3] = fmaf(hv, w3.y, acc[1][3]);
      acc[2][3] = fmaf(hv, w3.z, acc[2][3]);
      acc[3][3] = fmaf(hv, w3.w, acc[3][3]);
    }

#pragma unroll
    for (int c = 0; c < 4; ++c)
#pragma unroll
      for (int g = 0; g < 4; ++g) red[(w * 64 + lane) * 17 + c * 4 + g] = acc[c][g];
    __syncthreads();

    if (tid < 256) {
      const int b = tid >> 2;
      const int c = tid & 3;
      const int h = hbase + c;
      const float4 gxv =
          *(const float4*)(gx + ((size_t)(tt * 256 + blockIdx.x) * 64 + b) * 16 + c * 4);
      const float* gp = &gxv.x;
      float v[4];
#pragma unroll
      for (int g = 0; g < 4; ++g) {
        float s = gp[g];
#pragma unroll
        for (int ww = 0; ww < 8; ++ww) s += red[(ww * 64 + b) * 17 + c * 4 + g];
        v[g] = s;
      }
      const float cold = c_state[b * H_ + h];
      const float si = 1.f / (1.f + expf(-v[0]));
      const float sf = 1.f / (1.f + expf(-v[1]));
      const float gt = tanhf(v[2]);
      const float so = 1.f / (1.f + expf(-v[3]));
      const float cn = sf * cold + si * gt;
      const float hn = so * tanhf(cn);
      c_state[b * H_ + h] = cn;
      hout[h * 64 + b] = hn;
      ys[(size_t)b * (T_ * H_) + (size_t)t * H_ + h] = hn;
    }

    // ---- lightweight grid barrier (replaces cg::grid.sync) ----
    __syncthreads();                       // block done: all reads of hin + writes issued
    if (tid == 0) {
      __threadfence();                     // release hout/c/ys to agent scope
      __hip_atomic_fetch_add(bar, 1u, __ATOMIC_ACQ_REL, __HIP_MEMORY_SCOPE_AGENT);
      const unsigned target = (unsigned)NBLK * (unsigned)(t + 1);
      while (__hip_atomic_load(bar, __ATOMIC_ACQUIRE, __HIP_MEMORY_SCOPE_AGENT) < target) {
        __builtin_amdgcn_s_sleep(2);
      }
      __threadfence();                     // acquire: invalidate stale L1 before next step
    }
    __syncthreads();
  }
}

// ---------------- fallback: fused step (tiny ws) ----------------
__global__ __launch_bounds__(512) void k_lstm_step_fused(
    const float* __restrict__ xsrc, const float* __restrict__ Wi,
    const float* __restrict__ Wh, const float* __restrict__ bias,
    const float* __restrict__ hT_in, float* __restrict__ hT_out,
    float* __restrict__ c_state, float* __restrict__ ys_t) {
  __shared__ float red[8 * 64 * 17];
  const int tid = threadIdx.x;
  const int lane = tid & 63;
  const int w = tid >> 6;
  const int hbase = blockIdx.x * 4;
  float acc[4][4];
#pragma unroll
  for (int c = 0; c < 4; ++c)
#pragma unroll
    for (int g = 0; g < 4; ++g) acc[c][g] = 0.f;
  const int k0 = w * 128;
#pragma unroll 2
  for (int k = k0; k < k0 + 128; ++k) {
    const float hv = hT_in[k * 64 + lane];
    const float xv = xsrc[(size_t)lane * (T_ * D_) + k];
#pragma unroll
    for (int g = 0; g < 4; ++g) {
      const float4 wh = *(const float4*)(Wh + (size_t)k * NG_ + g * H_ + hbase);
      const float4 wi = *(const float4*)(Wi + (size_t)k * NG_ + g * H_ + hbase);
      acc[0][g] = fmaf(hv, wh.x, acc[0][g]);
      acc[1][g] = fmaf(hv, wh.y, acc[1][g]);
      acc[2][g] = fmaf(hv, wh.z, acc[2][g]);
      acc[3][g] = fmaf(hv, wh.w, acc[3][g]);
      acc[0][g] = fmaf(xv, wi.x, acc[0][g]);
      acc[1][g] = fmaf(xv, wi.y, acc[1][g]);
      acc[2][g] = fmaf(xv, wi.z, acc[2][g]);
      acc[3][g] = fmaf(xv, wi.w, acc[3][g]);
    }
  }
#pragma unroll
  for (int c = 0; c < 4; ++c)
#pragma unroll
    for (int g = 0; g < 4; ++g) red[(w * 64 + lane) * 17 + c * 4 + g] = acc[c][g];
  __syncthreads();
  if (tid < 256) {
    const int b = tid >> 2;
    const int c = tid & 3;
    const int h = hbase + c;
    float v[4];
#pragma unroll
    for (int g = 0; g < 4; ++g) {
      float s = bias[g * H_ + h];
#pragma unroll
      for (int ww = 0; ww < 8; ++ww) s += red[(ww * 64 + b) * 17 + c * 4 + g];
      v[g] = s;
    }
    const float cold = c_state[b * H_ + h];
    const float si = 1.f / (1.f + expf(-v[0]));
    const float sf = 1.f / (1.f + expf(-v[1]));
    const float gt = tanhf(v[2]);
    const float so = 1.f / (1.f + expf(-v[3]));
    const float cn = sf * cold + si * gt;
    const float hn = so * tanhf(cn);
    c_state[b * H_ + h] = cn;
    hT_out[h * 64 + b] = hn;
    ys_t[(size_t)b * (T_ * H_) + h] = hn;
  }
}

extern "C" void kernel_launch(void* const* d_in, const int* in_sizes, int n_in,
                              void* d_out, int out_size, void* d_ws, size_t ws_size,
                              hipStream_t stream) {
  const float* c0   = (const float*)d_in[0];
  const float* h0   = (const float*)d_in[1];
  const float* x    = (const float*)d_in[2];
  const float* Wi   = (const float*)d_in[3];
  const float* Wh   = (const float*)d_in[4];
  const float* bias = (const float*)d_in[5];

  float* out     = (float*)d_out;
  float* c_state = out;
  float* h_final = out + B_ * H_;
  float* ys      = out + 2 * B_ * H_;

  const size_t hbytes = (size_t)B_ * H_ * sizeof(float);
  unsigned* bar = (unsigned*)d_ws;                         // 1 KB reserved
  float* hA = (float*)((char*)d_ws + 1024);
  float* hB = hA + B_ * H_;
  float* gxbuf = hB + B_ * H_;

  const size_t slice = (size_t)256 * 64 * 16 * sizeof(float);  // 1 MB per t
  size_t fixed = 1024 + 2 * hbytes;
  size_t avail = (ws_size > fixed) ? ws_size - fixed : 0;
  int Tc = (int)(avail / slice);
  if (Tc > T_) Tc = T_;

  hipMemsetAsync(bar, 0, 1024, stream);   // reset barrier counter every launch
  hipMemcpyAsync(c_state, c0, hbytes, hipMemcpyDeviceToDevice, stream);
  k_trans_h_fwd<<<B_ * H_ / 256, 256, 0, stream>>>(h0, hA);

  const unsigned smem_recur = (16384 + 8704) * sizeof(float);  // 100352 B

  if (Tc >= 1) {
    for (int t0 = 0; t0 < T_; t0 += Tc) {
      const int tc = (T_ - t0 < Tc) ? (T_ - t0) : Tc;
      dim3 gg(256, tc);
      k_gx<<<gg, 512, 0, stream>>>(x, Wi, bias, gxbuf, t0);
      int t0v = t0, tcv = tc;
      void* args[] = {(void*)&Wh,  (void*)&gxbuf,   (void*)&hA,
                      (void*)&hB,  (void*)&c_state, (void*)&ys,
                      (void*)&bar, (void*)&t0v,     (void*)&tcv};
      hipLaunchCooperativeKernel((void*)k_recur, dim3(NBLK), dim3(512), args,
                                 smem_recur, stream);
    }
  } else {
    for (int t = 0; t < T_; ++t) {
      const float* hin = (t & 1) ? hB : hA;
      float* hout      = (t & 1) ? hA : hB;
      k_lstm_step_fused<<<256, 512, 0, stream>>>(
          x + (size_t)t * D_, Wi, Wh, bias, hin, hout, c_state,
          ys + (size_t)t * H_);
    }
  }
  k_trans_h_back<<<B_ * H_ / 256, 256, 0, stream>>>(hA, h_final);
}